// Round 1
// baseline (334.882 us; speedup 1.0000x reference)
//
#include <hip/hip_runtime.h>

#define N_NODES 50000
#define N_EDGES 800000
#define N_RELS  8
#define DIM     64

// ---------------------------------------------------------------------------
// Kernel A: hw[n][k][o] = sum_d h[n][d] * W[k][d][o]
// 512 threads = 8 waves; wave handles relation k = tid>>6, lane = output o.
// W[k][:,o] held in 64 VGPRs; h tile staged in LDS, read as broadcast float4.
// ---------------------------------------------------------------------------
__global__ __launch_bounds__(512) void k_hw(const float* __restrict__ h,
                                            const float* __restrict__ W,
                                            float* __restrict__ hw) {
    const int k = threadIdx.x >> 6;
    const int o = threadIdx.x & 63;

    float wreg[64];
#pragma unroll
    for (int d = 0; d < 64; ++d)
        wreg[d] = W[k * 4096 + d * 64 + o];   // coalesced across lanes

    __shared__ float hs[32][64];
    const int TN = 32;

    for (int n0 = blockIdx.x * TN; n0 < N_NODES; n0 += gridDim.x * TN) {
        __syncthreads();
        const int nmax = min(TN, N_NODES - n0);
        for (int i = threadIdx.x; i < nmax * 64; i += 512)
            hs[i >> 6][i & 63] = h[(size_t)n0 * 64 + i];
        __syncthreads();

        for (int j = 0; j < nmax; ++j) {
            const float4* hp = (const float4*)hs[j];
            float acc = 0.f;
#pragma unroll
            for (int q = 0; q < 16; ++q) {
                float4 hv = hp[q];          // LDS broadcast, conflict-free
                acc += hv.x * wreg[4 * q + 0];
                acc += hv.y * wreg[4 * q + 1];
                acc += hv.z * wreg[4 * q + 2];
                acc += hv.w * wreg[4 * q + 3];
            }
            hw[(size_t)(n0 + j) * 512 + k * 64 + o] = acc;  // 2KB/block contiguous
        }
    }
}

// ---------------------------------------------------------------------------
// Kernel B: per-edge gather + scale + atomic scatter. One wave per edge.
// ---------------------------------------------------------------------------
__global__ __launch_bounds__(256) void k_scatter(const float* __restrict__ hw,
                                                 const int* __restrict__ src,
                                                 const int* __restrict__ dst,
                                                 const int* __restrict__ rel,
                                                 const float* __restrict__ norm,
                                                 float* __restrict__ agg) {
    const int lane  = threadIdx.x & 63;
    const int warp  = (blockIdx.x * 256 + threadIdx.x) >> 6;
    const int nwarp = (gridDim.x * 256) >> 6;
    for (int e = warp; e < N_EDGES; e += nwarp) {
        const int   s  = src[e];
        const int   d2 = dst[e];
        const int   rr = rel[e];
        const float nm = norm[e];
        const float v  = hw[(size_t)s * 512 + rr * 64 + lane] * nm; // 256B coalesced
        atomicAdd(&agg[(size_t)d2 * 64 + lane], v);
    }
}

// ---------------------------------------------------------------------------
// Fallback (ws too small): per-edge direct matvec h[src] @ W[r], W from L2.
// ---------------------------------------------------------------------------
__global__ __launch_bounds__(256) void k_edge_direct(const float* __restrict__ h,
                                                     const float* __restrict__ W,
                                                     const int* __restrict__ src,
                                                     const int* __restrict__ dst,
                                                     const int* __restrict__ rel,
                                                     const float* __restrict__ norm,
                                                     float* __restrict__ agg) {
    const int lane  = threadIdx.x & 63;
    const int warp  = (blockIdx.x * 256 + threadIdx.x) >> 6;
    const int nwarp = (gridDim.x * 256) >> 6;
    for (int e = warp; e < N_EDGES; e += nwarp) {
        const int   s  = src[e];
        const int   d2 = dst[e];
        const int   rr = rel[e];
        const float nm = norm[e];
        const float4* hp = (const float4*)(h + (size_t)s * 64);
        const float*  Wr = W + (size_t)rr * 4096;
        float acc = 0.f;
#pragma unroll
        for (int q = 0; q < 16; ++q) {
            float4 hv = hp[q];
            acc += hv.x * Wr[(4 * q + 0) * 64 + lane];
            acc += hv.y * Wr[(4 * q + 1) * 64 + lane];
            acc += hv.z * Wr[(4 * q + 2) * 64 + lane];
            acc += hv.w * Wr[(4 * q + 3) * 64 + lane];
        }
        atomicAdd(&agg[(size_t)d2 * 64 + lane], acc * nm);
    }
}

// ---------------------------------------------------------------------------
// Kernel C: out = relu(agg + bias + h @ loop_weight). One wave per node.
// ---------------------------------------------------------------------------
__global__ __launch_bounds__(256) void k_final(float* __restrict__ out,
                                               const float* __restrict__ h,
                                               const float* __restrict__ lw,
                                               const float* __restrict__ bias) {
    __shared__ float lws[4096];
    for (int i = threadIdx.x; i < 4096; i += 256) lws[i] = lw[i];
    __syncthreads();

    const int lane  = threadIdx.x & 63;
    const int warp  = (blockIdx.x * 256 + threadIdx.x) >> 6;
    const int nwarp = (gridDim.x * 256) >> 6;
    const float b = bias[lane];

    for (int n = warp; n < N_NODES; n += nwarp) {
        const float4* hp = (const float4*)(h + (size_t)n * 64);
        float acc = b;
#pragma unroll
        for (int q = 0; q < 16; ++q) {
            float4 hv = hp[q];                       // broadcast load
            acc += hv.x * lws[(4 * q + 0) * 64 + lane];
            acc += hv.y * lws[(4 * q + 1) * 64 + lane];
            acc += hv.z * lws[(4 * q + 2) * 64 + lane];
            acc += hv.w * lws[(4 * q + 3) * 64 + lane];
        }
        const size_t idx = (size_t)n * 64 + lane;
        const float v = out[idx] + acc;
        out[idx] = v > 0.f ? v : 0.f;
    }
}

extern "C" void kernel_launch(void* const* d_in, const int* in_sizes, int n_in,
                              void* d_out, int out_size, void* d_ws, size_t ws_size,
                              hipStream_t stream) {
    const float* h    = (const float*)d_in[0];
    const float* norm = (const float*)d_in[1];
    const float* W    = (const float*)d_in[2];
    const float* lw   = (const float*)d_in[3];
    const float* bias = (const float*)d_in[4];
    const int*   src  = (const int*)d_in[5];
    const int*   dst  = (const int*)d_in[6];
    const int*   rel  = (const int*)d_in[7];
    float* out = (float*)d_out;

    // agg accumulates directly in d_out; must zero (harness poisons 0xAA).
    hipMemsetAsync(out, 0, (size_t)out_size * sizeof(float), stream);

    const size_t hw_bytes = (size_t)N_NODES * 512 * sizeof(float); // 102.4 MB
    if (ws_size >= hw_bytes) {
        float* hw = (float*)d_ws;
        k_hw<<<(N_NODES + 31) / 32, 512, 0, stream>>>(h, W, hw);
        k_scatter<<<2048, 256, 0, stream>>>(hw, src, dst, rel, norm, out);
    } else {
        k_edge_direct<<<2048, 256, 0, stream>>>(h, W, src, dst, rel, norm, out);
    }
    k_final<<<1024, 256, 0, stream>>>(out, h, lw, bias);
}

// Round 2
// 230.442 us; speedup vs baseline: 1.4532x; 1.4532x over previous
//
#include <hip/hip_runtime.h>

#define N_NODES 50000
#define N_EDGES 800000
#define N_RELS  8
#define DIM     64
#define SCAN_BLK 512
#define NB_SCAN ((N_NODES + SCAN_BLK - 1) / SCAN_BLK)   // 98

// ---------------------------------------------------------------------------
// Kernel A: hw[(n*8+k)*64+o] = sum_d h[n][d] * W[k][d][o]   (k=0..7)
//           hwloop[n*64+o]   = sum_d h[n][d] * lw[d][o]     (wave 8)
// 576 threads = 9 waves, one per "relation" (8 real + self-loop).
// h addresses are wave-uniform -> scalar (SMEM) loads; W column in 64 VGPRs.
// 4 split accumulators break the FMA dependence chain.
// ---------------------------------------------------------------------------
__global__ __launch_bounds__(576) void k_hw(const float* __restrict__ h,
                                            const float* __restrict__ W,
                                            const float* __restrict__ lw,
                                            float* __restrict__ hw,
                                            float* __restrict__ hwloop) {
    const int k = threadIdx.x >> 6;     // 0..8
    const int o = threadIdx.x & 63;
    const float* Wk = (k < 8) ? (W + (size_t)k * 4096) : lw;

    float wreg[64];
#pragma unroll
    for (int d = 0; d < 64; ++d)
        wreg[d] = Wk[d * 64 + o];       // coalesced across lanes

    const int TN = 16;                  // 3125 * 16 == 50000 exactly
    const int n0 = blockIdx.x * TN;
#pragma unroll 2
    for (int j = 0; j < TN; ++j) {
        const int n = n0 + j;
        const float* hp = h + (size_t)n * 64;   // uniform -> s_load
        float a0 = 0.f, a1 = 0.f, a2 = 0.f, a3 = 0.f;
#pragma unroll
        for (int d = 0; d < 64; d += 4) {
            a0 += hp[d + 0] * wreg[d + 0];
            a1 += hp[d + 1] * wreg[d + 1];
            a2 += hp[d + 2] * wreg[d + 2];
            a3 += hp[d + 3] * wreg[d + 3];
        }
        const float acc = (a0 + a1) + (a2 + a3);
        if (k < 8) hw[((size_t)n * 8 + k) * 64 + o] = acc;
        else       hwloop[(size_t)n * 64 + o] = acc;
    }
}

// ---------------------------------------------------------------------------
// CSR build: histogram -> 3-phase exclusive scan -> cursor fill
// ---------------------------------------------------------------------------
__global__ void k_hist(const int* __restrict__ dst, int* __restrict__ deg) {
    const int i = blockIdx.x * blockDim.x + threadIdx.x;
    const int stride = gridDim.x * blockDim.x;
    for (int e = i; e < N_EDGES; e += stride)
        atomicAdd(&deg[dst[e]], 1);
}

__global__ __launch_bounds__(SCAN_BLK) void k_scan_part(const int* __restrict__ deg,
                                                        int* __restrict__ bsum) {
    __shared__ int sh[SCAN_BLK];
    const int i = blockIdx.x * SCAN_BLK + threadIdx.x;
    sh[threadIdx.x] = (i < N_NODES) ? deg[i] : 0;
    __syncthreads();
    for (int s = SCAN_BLK / 2; s > 0; s >>= 1) {
        if (threadIdx.x < s) sh[threadIdx.x] += sh[threadIdx.x + s];
        __syncthreads();
    }
    if (threadIdx.x == 0) bsum[blockIdx.x] = sh[0];
}

__global__ void k_scan_mid(const int* __restrict__ bsum, int* __restrict__ bpref,
                           int* __restrict__ off) {
    if (threadIdx.x == 0 && blockIdx.x == 0) {
        int run = 0;
        for (int b = 0; b < NB_SCAN; ++b) { bpref[b] = run; run += bsum[b]; }
        off[N_NODES] = run;   // == N_EDGES
    }
}

__global__ __launch_bounds__(SCAN_BLK) void k_scan_final(const int* __restrict__ deg,
                                                         const int* __restrict__ bpref,
                                                         int* __restrict__ off,
                                                         int* __restrict__ cursor) {
    __shared__ int sh[SCAN_BLK];
    const int i = blockIdx.x * SCAN_BLK + threadIdx.x;
    const int v = (i < N_NODES) ? deg[i] : 0;
    sh[threadIdx.x] = v;
    __syncthreads();
    for (int s = 1; s < SCAN_BLK; s <<= 1) {
        const int t = (threadIdx.x >= s) ? sh[threadIdx.x - s] : 0;
        __syncthreads();
        sh[threadIdx.x] += t;
        __syncthreads();
    }
    if (i < N_NODES) {
        const int excl = bpref[blockIdx.x] + sh[threadIdx.x] - v;
        off[i] = excl;
        cursor[i] = excl;
    }
}

__global__ void k_csrfill(const int* __restrict__ src, const int* __restrict__ dst,
                          const int* __restrict__ rel, const float* __restrict__ norm,
                          int* __restrict__ cursor, int2* __restrict__ payload) {
    const int i = blockIdx.x * blockDim.x + threadIdx.x;
    const int stride = gridDim.x * blockDim.x;
    for (int e = i; e < N_EDGES; e += stride) {
        const int d = dst[e];
        const int pos = atomicAdd(&cursor[d], 1);
        payload[pos] = make_int2(src[e] * 8 + rel[e], __float_as_int(norm[e]));
    }
}

// ---------------------------------------------------------------------------
// Kernel B: one wave per node; sum its CSR edge list + self-loop + bias, ReLU.
// Single coalesced 256B write per node — no f32 atomics anywhere.
// ---------------------------------------------------------------------------
__global__ __launch_bounds__(256) void k_gather(const float* __restrict__ hw,
                                                const float* __restrict__ hwloop,
                                                const int* __restrict__ off,
                                                const int2* __restrict__ payload,
                                                const float* __restrict__ bias,
                                                float* __restrict__ out) {
    const int lane = threadIdx.x & 63;
    const int n = (blockIdx.x * 256 + threadIdx.x) >> 6;
    if (n >= N_NODES) return;
    const int beg = off[n];
    const int end = off[n + 1];

    float acc = bias[lane] + hwloop[(size_t)n * 64 + lane];
    int t = beg;
    for (; t + 1 < end; t += 2) {       // 2-way unroll overlaps the gathers
        const int2 p0 = payload[t];
        const int2 p1 = payload[t + 1];
        const float v0 = hw[(size_t)p0.x * 64 + lane];
        const float v1 = hw[(size_t)p1.x * 64 + lane];
        acc += v0 * __int_as_float(p0.y);
        acc += v1 * __int_as_float(p1.y);
    }
    if (t < end) {
        const int2 p = payload[t];
        acc += hw[(size_t)p.x * 64 + lane] * __int_as_float(p.y);
    }
    out[(size_t)n * 64 + lane] = fmaxf(acc, 0.f);
}

// ---------------------------------------------------------------------------
// Fallback path (ws too small): per-edge direct matvec + f32 atomics + finish.
// ---------------------------------------------------------------------------
__global__ __launch_bounds__(256) void k_edge_direct(const float* __restrict__ h,
                                                     const float* __restrict__ W,
                                                     const int* __restrict__ src,
                                                     const int* __restrict__ dst,
                                                     const int* __restrict__ rel,
                                                     const float* __restrict__ norm,
                                                     float* __restrict__ agg) {
    const int lane  = threadIdx.x & 63;
    const int warp  = (blockIdx.x * 256 + threadIdx.x) >> 6;
    const int nwarp = (gridDim.x * 256) >> 6;
    for (int e = warp; e < N_EDGES; e += nwarp) {
        const int   s  = src[e];
        const int   d2 = dst[e];
        const int   rr = rel[e];
        const float nm = norm[e];
        const float4* hp = (const float4*)(h + (size_t)s * 64);
        const float*  Wr = W + (size_t)rr * 4096;
        float acc = 0.f;
#pragma unroll
        for (int q = 0; q < 16; ++q) {
            float4 hv = hp[q];
            acc += hv.x * Wr[(4 * q + 0) * 64 + lane];
            acc += hv.y * Wr[(4 * q + 1) * 64 + lane];
            acc += hv.z * Wr[(4 * q + 2) * 64 + lane];
            acc += hv.w * Wr[(4 * q + 3) * 64 + lane];
        }
        atomicAdd(&agg[(size_t)d2 * 64 + lane], acc * nm);
    }
}

__global__ __launch_bounds__(256) void k_final(float* __restrict__ out,
                                               const float* __restrict__ h,
                                               const float* __restrict__ lw,
                                               const float* __restrict__ bias) {
    __shared__ float lws[4096];
    for (int i = threadIdx.x; i < 4096; i += 256) lws[i] = lw[i];
    __syncthreads();
    const int lane  = threadIdx.x & 63;
    const int warp  = (blockIdx.x * 256 + threadIdx.x) >> 6;
    const int nwarp = (gridDim.x * 256) >> 6;
    const float b = bias[lane];
    for (int n = warp; n < N_NODES; n += nwarp) {
        const float4* hp = (const float4*)(h + (size_t)n * 64);
        float acc = b;
#pragma unroll
        for (int q = 0; q < 16; ++q) {
            float4 hv = hp[q];
            acc += hv.x * lws[(4 * q + 0) * 64 + lane];
            acc += hv.y * lws[(4 * q + 1) * 64 + lane];
            acc += hv.z * lws[(4 * q + 2) * 64 + lane];
            acc += hv.w * lws[(4 * q + 3) * 64 + lane];
        }
        const size_t idx = (size_t)n * 64 + lane;
        const float v = out[idx] + acc;
        out[idx] = v > 0.f ? v : 0.f;
    }
}

extern "C" void kernel_launch(void* const* d_in, const int* in_sizes, int n_in,
                              void* d_out, int out_size, void* d_ws, size_t ws_size,
                              hipStream_t stream) {
    const float* h    = (const float*)d_in[0];
    const float* norm = (const float*)d_in[1];
    const float* W    = (const float*)d_in[2];
    const float* lw   = (const float*)d_in[3];
    const float* bias = (const float*)d_in[4];
    const int*   src  = (const int*)d_in[5];
    const int*   dst  = (const int*)d_in[6];
    const int*   rel  = (const int*)d_in[7];
    float* out = (float*)d_out;

    // --- workspace layout -------------------------------------------------
    char*  ws      = (char*)d_ws;
    float* hw      = (float*)ws;                              // 25.6M floats
    float* hwloop  = hw + (size_t)N_NODES * 8 * 64;           // 3.2M floats
    int*   off     = (int*)(hwloop + (size_t)N_NODES * 64);   // N+1 (pad 50016)
    int*   cursor  = off + (N_NODES + 16);
    int*   bsum    = cursor + (N_NODES + 16);
    int*   bpref   = bsum + 128;
    int*   deg     = bpref + 128;
    int2*  payload = (int2*)(deg + (N_NODES + 16));           // 800K int2
    const size_t need = (size_t)((char*)(payload + N_EDGES) - ws);

    if (ws_size >= need) {
        hipMemsetAsync(deg, 0, N_NODES * sizeof(int), stream);
        k_hw<<<N_NODES / 16, 576, 0, stream>>>(h, W, lw, hw, hwloop);
        k_hist<<<1024, 256, 0, stream>>>(dst, deg);
        k_scan_part<<<NB_SCAN, SCAN_BLK, 0, stream>>>(deg, bsum);
        k_scan_mid<<<1, 64, 0, stream>>>(bsum, bpref, off);
        k_scan_final<<<NB_SCAN, SCAN_BLK, 0, stream>>>(deg, bpref, off, cursor);
        k_csrfill<<<1024, 256, 0, stream>>>(src, dst, rel, norm, cursor, payload);
        k_gather<<<(N_NODES + 3) / 4, 256, 0, stream>>>(hw, hwloop, off, payload, bias, out);
    } else {
        // fallback: atomic scatter path
        hipMemsetAsync(out, 0, (size_t)out_size * sizeof(float), stream);
        k_edge_direct<<<2048, 256, 0, stream>>>(h, W, src, dst, rel, norm, out);
        k_final<<<1024, 256, 0, stream>>>(out, h, lw, bias);
    }
}